// Round 8
// baseline (99.714 us; speedup 1.0000x reference)
//
#include <hip/hip_runtime.h>
#include <hip/hip_bf16.h>
#include <math.h>

#define BB   8
#define CC   80
#define HH   128
#define WW   128
#define HWN  16384
#define KTOP 100
#define NSTRIP 8
#define SR   16
#define LR   (SR + 4)
#define SCAP 512
#define CAPB 65536          // per-batch slab capacity; real data ~52.4K (R6/R7-validated)
#define NSEG 64             // kred segments per batch; NSEG*1024 == CAPB

typedef unsigned long long ull;

__device__ __forceinline__ float sigmoidf_(float x) {
    // bitwise-matched vs jax.nn.sigmoid (R1/R3/R4/R6/R7)
    if (x >= 0.0f) return 1.0f / (1.0f + expf(-x));
    float e = expf(x);
    return e / (1.0f + e);
}

// value desc, class asc, hw asc; unique per (map,hw). Ordering == reference
// two-stage top-k (proof R2-R4, bitwise-validated through R7).
__device__ __forceinline__ ull makekey(float v, int cls, int hw) {
    return ((ull)__float_as_uint(v) << 21)
         | ((ull)(127 - cls) << 14)
         | (ull)(16383 - hw);
}

// ---- Kernel A: sigmoid + fused 5x5 peak NMS per 16-row strip, append keys ----
// NOTE: no min-waves bound — R7's (256,8) forced VGPR=20 + scratch spills
// (WRITE_SIZE 3.6MB vs 0.45MB intended). LDS 14.8KB already allows 10 blocks/CU.
__global__ __launch_bounds__(256) void knms(const float* __restrict__ logits,
                                            ull* __restrict__ slab,
                                            int* __restrict__ counts) {
    __shared__ __align__(16) float s[LR][WW];    // 10 KB sigmoid tile (halo-clamped)
    __shared__ ull cand[SCAP];                   // 4 KB
    __shared__ int cnt, gbase;

    const int tid   = threadIdx.x;
    const int map   = blockIdx.x >> 3;           // b*CC + c
    const int strip = blockIdx.x & 7;
    const int cls   = map % CC;
    const int b     = map / CC;
    const int R0    = strip * SR;
    const float* __restrict__ src = logits + (size_t)map * HWN;
    if (tid == 0) cnt = 0;

    // stage: strided float4 loop (R4-proven codegen, no spills)
    for (int v = tid; v < LR * 32; v += 256) {
        const int lr = v >> 5, c4 = (v & 31) << 2;
        int gr = R0 - 2 + lr;
        gr = gr < 0 ? 0 : (gr > HH - 1 ? HH - 1 : gr);
        const float4 f = *reinterpret_cast<const float4*>(src + (size_t)gr * WW + c4);
        float4 o;
        o.x = sigmoidf_(f.x); o.y = sigmoidf_(f.y);
        o.z = sigmoidf_(f.z); o.w = sigmoidf_(f.w);
        *reinterpret_cast<float4*>(&s[lr][c4]) = o;
    }
    __syncthreads();

    // fused 5x5 window max per center quad (registers only), keep, compact
    for (int i = tid; i < SR * 32; i += 256) {
        const int r = i >> 5, c4 = (i & 31) << 2;
        const bool hasL = (c4 >= 4), hasR = (c4 <= WW - 8);
        float wv[12];
#pragma unroll
        for (int k = 0; k < 12; ++k) wv[k] = -INFINITY;
#pragma unroll
        for (int rr = 0; rr < 5; ++rr) {
            const float4 C = *reinterpret_cast<const float4*>(&s[r + rr][c4]);
            wv[4] = fmaxf(wv[4], C.x); wv[5] = fmaxf(wv[5], C.y);
            wv[6] = fmaxf(wv[6], C.z); wv[7] = fmaxf(wv[7], C.w);
            if (hasL) {
                const float4 L = *reinterpret_cast<const float4*>(&s[r + rr][c4 - 4]);
                wv[0] = fmaxf(wv[0], L.x); wv[1] = fmaxf(wv[1], L.y);
                wv[2] = fmaxf(wv[2], L.z); wv[3] = fmaxf(wv[3], L.w);
            }
            if (hasR) {
                const float4 R = *reinterpret_cast<const float4*>(&s[r + rr][c4 + 4]);
                wv[8] = fmaxf(wv[8], R.x); wv[9] = fmaxf(wv[9], R.y);
                wv[10] = fmaxf(wv[10], R.z); wv[11] = fmaxf(wv[11], R.w);
            }
        }
        const float4 cen = *reinterpret_cast<const float4*>(&s[r + 2][c4]);
        const float cv[4] = {cen.x, cen.y, cen.z, cen.w};
#pragma unroll
        for (int j = 0; j < 4; ++j) {
            const float m = fmaxf(fmaxf(wv[2 + j], wv[3 + j]),
                                  fmaxf(fmaxf(wv[4 + j], wv[5 + j]), wv[6 + j]));
            if (cv[j] == m) {          // exact reference keep: sigma == 5x5 sigma-max
                const int slot = atomicAdd(&cnt, 1);
                if (slot < SCAP)
                    cand[slot] = makekey(cv[j], cls, ((R0 + r) << 7) | (c4 + j));
            }
        }
    }
    __syncthreads();

    const int n = cnt < SCAP ? cnt : SCAP;
    if (tid == 0) gbase = atomicAdd(counts + b, n);
    __syncthreads();
    const int gb = gbase;
    for (int i = tid; i < n; i += 256) {
        const int gi = gb + i;
        if (gi < CAPB) slab[(size_t)b * CAPB + gi] = cand[i];
    }
}

// ---- in-register wave bitonic helpers (64 lanes; R6/R7-validated) ----
__device__ __forceinline__ ull sort64_desc(ull v, int lane) {
    for (int k = 2; k <= 64; k <<= 1) {
        for (int j = k >> 1; j >= 1; j >>= 1) {
            const ull p = __shfl_xor(v, j, 64);
            const bool km = (((lane & k) == 0) != ((lane & j) != 0));
            v = (km == (p > v)) ? p : v;
        }
    }
    return v;
}

__device__ __forceinline__ void bmerge128(ull& a0, ull& a1, int lane) {
    const ull t0 = a0 > a1 ? a0 : a1;
    a1 = a0 > a1 ? a1 : a0;
    a0 = t0;
    for (int j = 32; j >= 1; j >>= 1) {
        const ull p0 = __shfl_xor(a0, j, 64);
        const ull p1 = __shfl_xor(a1, j, 64);
        const bool km = ((lane & j) == 0);
        a0 = (km == (p0 > a0)) ? p0 : a0;
        a1 = (km == (p1 > a1)) ? p1 : a1;
    }
}

// LDS tournament: NCH sorted desc 128-lists -> top-128 in ch[0] (R4-validated)
template <int NCH, int NT>
__device__ __forceinline__ void tourney(ull (*ch)[128]) {
    int nch = NCH;
    while (nch > 1) {
        const int newn  = (nch + 1) >> 1;
        const int npair = nch - newn;
        for (int t = threadIdx.x; t < npair * 128; t += NT) {
            const int p = t >> 7, i = t & 127;
            ull a = ch[p][i], bv = ch[p + newn][127 - i];
            if (a < bv) { ch[p][i] = bv; ch[p + newn][127 - i] = a; }
        }
        __syncthreads();
        for (int j = 64; j >= 1; j >>= 1) {
            for (int t = threadIdx.x; t < npair * 64; t += NT) {
                const int p = t >> 6, q = t & 63;
                const int i = ((q & ~(j - 1)) << 1) | (q & (j - 1));
                ull a = ch[p][i], bv = ch[p][i | j];
                if (a < bv) { ch[p][i] = bv; ch[p][i | j] = a; }
            }
            __syncthreads();
        }
        nch = newn;
    }
}

// ---- Kernel B: per 1024-key slab segment -> sorted top-128 (512 blocks) ----
__global__ __launch_bounds__(256) void kred(const ull* __restrict__ slab,
                                            const int* __restrict__ counts,
                                            ull* __restrict__ lists) {
    __shared__ ull ls[4][128];
    const int tid = threadIdx.x, w = tid >> 6, lane = tid & 63;
    const int b = blockIdx.x >> 6, seg = blockIdx.x & (NSEG - 1);

    int n = counts[b];
    n = n < CAPB ? n : CAPB;
    int avail = n - seg * 1024;
    avail = avail < 0 ? 0 : (avail > 1024 ? 1024 : avail);
    const ull* __restrict__ base = slab + (size_t)b * CAPB + seg * 1024;

    ull a0 = 0ULL, a1 = 0ULL;
#pragma unroll
    for (int c = 0; c < 4; ++c) {
        const int idx = (w * 4 + c) * 64 + lane;
        ull v = (idx < avail) ? base[idx] : 0ULL;
        v = sort64_desc(v, lane);
        const ull rv = __shfl(v, 63 - lane, 64);
        a1 = a1 > rv ? a1 : rv;
        bmerge128(a0, a1, lane);
    }
    ls[w][lane] = a0;
    ls[w][64 + lane] = a1;

    for (int half = 2; half >= 1; half >>= 1) {
        __syncthreads();
        ull z0 = 0ULL, z1 = 0ULL;
        const bool act = (w < half);
        if (act) {
            const ull l0 = ls[2 * w][lane];
            const ull l1 = ls[2 * w][64 + lane];
            const ull r1r = ls[2 * w + 1][127 - lane];
            const ull r0r = ls[2 * w + 1][63 - lane];
            z0 = l0 > r1r ? l0 : r1r;
            z1 = l1 > r0r ? l1 : r0r;
            bmerge128(z0, z1, lane);
        }
        __syncthreads();
        if (act) { ls[w][lane] = z0; ls[w][64 + lane] = z1; }
    }
    __syncthreads();
    if (tid < 128)
        lists[(size_t)blockIdx.x * 128 + tid] = ls[0][tid];
}

// ---- Kernel C1: merge 8 segment lists -> 1 (64 blocks) ----
__global__ __launch_bounds__(256) void kred2(const ull* __restrict__ lists,
                                             ull* __restrict__ glists) {
    __shared__ ull ch[8][128];                   // 8 KB
    const int tid = threadIdx.x;
    for (int t = tid; t < 8 * 128; t += 256)
        ch[t >> 7][t & 127] = lists[(size_t)blockIdx.x * 8 * 128 + t];
    __syncthreads();
    tourney<8, 256>(ch);
    if (tid < 128)
        glists[(size_t)blockIdx.x * 128 + tid] = ch[0][tid];
}

// ---- Kernel C2: per batch merge 8 group lists -> top-100 + decode (8 blocks) ----
__global__ __launch_bounds__(256) void kfin(const ull* __restrict__ glists,
                                            const float* __restrict__ txty,
                                            const float* __restrict__ twth,
                                            float* __restrict__ out) {
    __shared__ ull ch[8][128];                   // 8 KB
    const int tid = threadIdx.x, b = blockIdx.x;
    for (int t = tid; t < 8 * 128; t += 256)
        ch[t >> 7][t & 127] = glists[(size_t)b * 8 * 128 + t];
    __syncthreads();
    tourney<8, 256>(ch);

    if (tid < KTOP) {
        const ull key = ch[0][tid];
        const int hw  = 16383 - (int)(key & 0x3FFFULL);
        const int cls = 127 - (int)((key >> 14) & 0x7FULL);
        const float sc = __uint_as_float((unsigned int)(key >> 21));

        // out layout (float32): score[0..800) | bbox[800..4000) | inds[4000..4800) | clses[4800..5600)
        out[b * KTOP + tid]        = sc;
        out[4000 + b * KTOP + tid] = (float)hw;
        out[4800 + b * KTOP + tid] = (float)cls;

        const int xx = hw & 127, yy = hw >> 7;
        const float* __restrict__ t = txty + (size_t)b * 2 * HWN;
        const float* __restrict__ u = twth + (size_t)b * 2 * HWN;
        const float tx = t[hw], ty = t[HWN + hw];
        const float tw = u[hw], th = u[HWN + hw];

        const float cx = (sigmoidf_(tx) + (float)xx) * 4.0f;
        const float cy = (sigmoidf_(ty) + (float)yy) * 4.0f;
        const float bw = expf(tw) * 4.0f;
        const float bh = expf(th) * 4.0f;

        const float inv = 1.0f / 512.0f;
        float x1 = (cx - bw * 0.5f) * inv;
        float y1 = (cy - bh * 0.5f) * inv;
        float x2 = (cx + bw * 0.5f) * inv;
        float y2 = (cy + bh * 0.5f) * inv;
        x1 = fminf(fmaxf(x1, 0.0f), 1.0f);
        y1 = fminf(fmaxf(y1, 0.0f), 1.0f);
        x2 = fminf(fmaxf(x2, 0.0f), 1.0f);
        y2 = fminf(fmaxf(y2, 0.0f), 1.0f);

        float* bb = out + 800 + (size_t)(b * KTOP + tid) * 4;
        bb[0] = x1; bb[1] = y1; bb[2] = x2; bb[3] = y2;
    }
}

extern "C" void kernel_launch(void* const* d_in, const int* in_sizes, int n_in,
                              void* d_out, int out_size, void* d_ws, size_t ws_size,
                              hipStream_t stream) {
    const float* cls_logits = (const float*)d_in[0];
    const float* txty       = (const float*)d_in[1];
    const float* twth       = (const float*)d_in[2];
    float* out = (float*)d_out;

    // ws: slab 4,194,304 | counts 256 | lists 512*128*8 = 524,288 | glists 64*128*8 = 65,536
    ull* slab   = (ull*)d_ws;
    int* counts = (int*)((char*)d_ws + (size_t)BB * CAPB * 8);
    ull* lists  = (ull*)((char*)d_ws + (size_t)BB * CAPB * 8 + 256);
    ull* glists = (ull*)((char*)d_ws + (size_t)BB * CAPB * 8 + 256 + 524288);

    hipMemsetAsync(counts, 0, BB * sizeof(int), stream);
    knms <<<BB * CC * NSTRIP, 256, 0, stream>>>(cls_logits, slab, counts);
    kred <<<BB * NSEG,        256, 0, stream>>>(slab, counts, lists);
    kred2<<<BB * 8,           256, 0, stream>>>(lists, glists);
    kfin <<<BB,               256, 0, stream>>>(glists, txty, twth, out);
}

// Round 9
// 96.965 us; speedup vs baseline: 1.0284x; 1.0284x over previous
//
#include <hip/hip_runtime.h>
#include <hip/hip_bf16.h>
#include <math.h>

#define BB   8
#define CC   80
#define HH   128
#define WW   128
#define HWN  16384
#define KTOP 100
#define NSTRIP 8
#define SR   16
#define LR   (SR + 4)
#define SCAP 512
#define CAPB 65536          // per-batch slab capacity; real data ~52.4K (R6-R8 validated)
#define NSEG 64             // kred segments per batch; NSEG*1024 == CAPB

typedef unsigned long long ull;

__device__ __forceinline__ float sigmoidf_(float x) {
    // bitwise-matched vs jax.nn.sigmoid (R1/R3/R4/R6-R8)
    if (x >= 0.0f) return 1.0f / (1.0f + expf(-x));
    float e = expf(x);
    return e / (1.0f + e);
}

// value desc, class asc, hw asc; unique per (map,hw). Ordering == reference
// two-stage top-k (proof R2-R4, bitwise-validated through R8).
__device__ __forceinline__ ull makekey(float v, int cls, int hw) {
    return ((ull)__float_as_uint(v) << 21)
         | ((ull)(127 - cls) << 14)
         | (ull)(16383 - hw);
}

// ---- Kernel A: sigmoid + 5x5 peak NMS; V-max in regs, H-max via shfl ----
// All-scalar inner loop (no arrays): rule-#20 scratch demotion killed R7/R8
// (VGPR=20). Every value below is a named scalar.
__global__ __launch_bounds__(256) void knms(const float* __restrict__ logits,
                                            ull* __restrict__ slab,
                                            int* __restrict__ counts) {
    __shared__ __align__(16) float s[LR][WW];    // 10 KB sigmoid tile (halo-clamped)
    __shared__ ull cand[SCAP];                   // 4 KB
    __shared__ int cnt, gbase;

    const int tid   = threadIdx.x;
    const int map   = blockIdx.x >> 3;           // b*CC + c
    const int strip = blockIdx.x & 7;
    const int cls   = map % CC;
    const int b     = map / CC;
    const int R0    = strip * SR;
    const float* __restrict__ src = logits + (size_t)map * HWN;
    if (tid == 0) cnt = 0;

    // stage sigmoid tile, float4, halo rows clamped (== -inf pad for window max)
    for (int v = tid; v < LR * 32; v += 256) {
        const int lr = v >> 5, c4 = (v & 31) << 2;
        int gr = R0 - 2 + lr;
        gr = gr < 0 ? 0 : (gr > HH - 1 ? HH - 1 : gr);
        const float4 f = *reinterpret_cast<const float4*>(src + (size_t)gr * WW + c4);
        float4 o;
        o.x = sigmoidf_(f.x); o.y = sigmoidf_(f.y);
        o.z = sigmoidf_(f.z); o.w = sigmoidf_(f.w);
        *reinterpret_cast<float4*>(&s[lr][c4]) = o;
    }
    __syncthreads();

    // 8 rows x 32 quad-lanes per iteration; 2 iterations cover SR=16
    const int q    = tid & 31;           // quad index within row (col = 4q..4q+3)
    const int lane = tid & 63;
    const int c0   = q << 2;
    for (int r = (tid >> 5); r < SR; r += 8) {
        const float4 f0 = *reinterpret_cast<const float4*>(&s[r    ][c0]);
        const float4 f1 = *reinterpret_cast<const float4*>(&s[r + 1][c0]);
        const float4 f2 = *reinterpret_cast<const float4*>(&s[r + 2][c0]);
        const float4 f3 = *reinterpret_cast<const float4*>(&s[r + 3][c0]);
        const float4 f4 = *reinterpret_cast<const float4*>(&s[r + 4][c0]);
        // vertical 5-max per column (center row = f2)
        const float vx = fmaxf(fmaxf(f0.x, f1.x), fmaxf(fmaxf(f2.x, f3.x), f4.x));
        const float vy = fmaxf(fmaxf(f0.y, f1.y), fmaxf(fmaxf(f2.y, f3.y), f4.y));
        const float vz = fmaxf(fmaxf(f0.z, f1.z), fmaxf(fmaxf(f2.z, f3.z), f4.z));
        const float vw = fmaxf(fmaxf(f0.w, f1.w), fmaxf(fmaxf(f2.w, f3.w), f4.w));
        // neighbor vm via shuffle (same wave row group; edges masked)
        float Lz = __shfl(vz, lane - 1, 64);
        float Lw = __shfl(vw, lane - 1, 64);
        float Rx = __shfl(vx, lane + 1, 64);
        float Ry = __shfl(vy, lane + 1, 64);
        Lz = (q == 0)  ? -INFINITY : Lz;
        Lw = (q == 0)  ? -INFINITY : Lw;
        Rx = (q == 31) ? -INFINITY : Rx;
        Ry = (q == 31) ? -INFINITY : Ry;
        // horizontal 5-max -> full 5x5 window max per pixel
        const float zw = fmaxf(vz, vw);
        const float xy = fmaxf(vx, vy);
        const float m0 = fmaxf(fmaxf(Lz, Lw), fmaxf(xy, vz));
        const float m1 = fmaxf(Lw, fmaxf(xy, zw));
        const float m2 = fmaxf(fmaxf(xy, zw), Rx);
        const float m3 = fmaxf(fmaxf(vy, zw), fmaxf(Rx, Ry));
        const int hwbase = ((R0 + r) << 7) | c0;
        if (f2.x == m0) { const int t = atomicAdd(&cnt, 1); if (t < SCAP) cand[t] = makekey(f2.x, cls, hwbase); }
        if (f2.y == m1) { const int t = atomicAdd(&cnt, 1); if (t < SCAP) cand[t] = makekey(f2.y, cls, hwbase + 1); }
        if (f2.z == m2) { const int t = atomicAdd(&cnt, 1); if (t < SCAP) cand[t] = makekey(f2.z, cls, hwbase + 2); }
        if (f2.w == m3) { const int t = atomicAdd(&cnt, 1); if (t < SCAP) cand[t] = makekey(f2.w, cls, hwbase + 3); }
    }
    __syncthreads();

    const int n = cnt < SCAP ? cnt : SCAP;
    if (tid == 0) gbase = atomicAdd(counts + b, n);
    __syncthreads();
    const int gb = gbase;
    for (int i = tid; i < n; i += 256) {
        const int gi = gb + i;
        if (gi < CAPB) slab[(size_t)b * CAPB + gi] = cand[i];
    }
}

// ---- in-register wave bitonic helpers (64 lanes; R6-R8 validated) ----
__device__ __forceinline__ ull sort64_desc(ull v, int lane) {
    for (int k = 2; k <= 64; k <<= 1) {
        for (int j = k >> 1; j >= 1; j >>= 1) {
            const ull p = __shfl_xor(v, j, 64);
            const bool km = (((lane & k) == 0) != ((lane & j) != 0));
            v = (km == (p > v)) ? p : v;
        }
    }
    return v;
}

__device__ __forceinline__ void bmerge128(ull& a0, ull& a1, int lane) {
    const ull t0 = a0 > a1 ? a0 : a1;
    a1 = a0 > a1 ? a1 : a0;
    a0 = t0;
    for (int j = 32; j >= 1; j >>= 1) {
        const ull p0 = __shfl_xor(a0, j, 64);
        const ull p1 = __shfl_xor(a1, j, 64);
        const bool km = ((lane & j) == 0);
        a0 = (km == (p0 > a0)) ? p0 : a0;
        a1 = (km == (p1 > a1)) ? p1 : a1;
    }
}

// ---- Kernel B: per 1024-key slab segment -> sorted top-128 (512 blocks x 8 waves) ----
__global__ __launch_bounds__(512) void kred(const ull* __restrict__ slab,
                                            const int* __restrict__ counts,
                                            ull* __restrict__ lists) {
    __shared__ ull ls[8][128];
    const int tid = threadIdx.x, w = tid >> 6, lane = tid & 63;
    const int b = blockIdx.x >> 6, seg = blockIdx.x & (NSEG - 1);

    int n = counts[b];
    n = n < CAPB ? n : CAPB;
    int avail = n - seg * 1024;
    avail = avail < 0 ? 0 : (avail > 1024 ? 1024 : avail);
    const ull* __restrict__ base = slab + (size_t)b * CAPB + seg * 1024;

    // each wave: 2 chunks of 64 -> sorted-128 in regs
    ull a0 = 0ULL, a1 = 0ULL;
#pragma unroll
    for (int c = 0; c < 2; ++c) {
        const int idx = (w * 2 + c) * 64 + lane;
        ull v = (idx < avail) ? base[idx] : 0ULL;
        v = sort64_desc(v, lane);
        const ull rv = __shfl(v, 63 - lane, 64);
        a1 = a1 > rv ? a1 : rv;
        bmerge128(a0, a1, lane);
    }
    ls[w][lane] = a0;
    ls[w][64 + lane] = a1;

    // merge 8 wave lists -> 1 (three rounds)
    for (int half = 4; half >= 1; half >>= 1) {
        __syncthreads();
        ull z0 = 0ULL, z1 = 0ULL;
        const bool act = (w < half);
        if (act) {
            const ull l0 = ls[2 * w][lane];
            const ull l1 = ls[2 * w][64 + lane];
            const ull r1r = ls[2 * w + 1][127 - lane];
            const ull r0r = ls[2 * w + 1][63 - lane];
            z0 = l0 > r1r ? l0 : r1r;
            z1 = l1 > r0r ? l1 : r0r;
            bmerge128(z0, z1, lane);
        }
        __syncthreads();
        if (act) { ls[w][lane] = z0; ls[w][64 + lane] = z1; }
    }
    __syncthreads();
    if (tid < 128)
        lists[(size_t)blockIdx.x * 128 + tid] = ls[0][tid];
}

// ---- Kernel C: per batch merge 64 sorted lists -> top-100 + decode (8 blocks) ----
__global__ __launch_bounds__(1024) void kfin(const ull* __restrict__ lists,
                                             const float* __restrict__ txty,
                                             const float* __restrict__ twth,
                                             float* __restrict__ out) {
    __shared__ ull ch[NSEG][128];                // 64 KB
    const int tid = threadIdx.x, b = blockIdx.x;

    for (int t = tid; t < NSEG * 128; t += 1024)
        ch[t >> 7][t & 127] = lists[(size_t)b * NSEG * 128 + t];
    __syncthreads();

    // tournament 64 -> 1, keep top-128 each round (R4-validated valley+merge)
    int nch = NSEG;
    while (nch > 1) {
        const int newn  = (nch + 1) >> 1;
        const int npair = nch - newn;
        for (int t = tid; t < npair * 128; t += 1024) {
            const int p = t >> 7, i = t & 127;
            ull a = ch[p][i], bv = ch[p + newn][127 - i];
            if (a < bv) { ch[p][i] = bv; ch[p + newn][127 - i] = a; }
        }
        __syncthreads();
        for (int j = 64; j >= 1; j >>= 1) {
            for (int t = tid; t < npair * 64; t += 1024) {
                const int p = t >> 6, qq = t & 63;
                const int i = ((qq & ~(j - 1)) << 1) | (qq & (j - 1));
                ull a = ch[p][i], bv = ch[p][i | j];
                if (a < bv) { ch[p][i] = bv; ch[p][i | j] = a; }
            }
            __syncthreads();
        }
        nch = newn;
    }

    if (tid < KTOP) {
        const ull key = ch[0][tid];
        const int hw  = 16383 - (int)(key & 0x3FFFULL);
        const int cls = 127 - (int)((key >> 14) & 0x7FULL);
        const float sc = __uint_as_float((unsigned int)(key >> 21));

        // out layout (float32): score[0..800) | bbox[800..4000) | inds[4000..4800) | clses[4800..5600)
        out[b * KTOP + tid]        = sc;
        out[4000 + b * KTOP + tid] = (float)hw;
        out[4800 + b * KTOP + tid] = (float)cls;

        const int xx = hw & 127, yy = hw >> 7;
        const float* __restrict__ t = txty + (size_t)b * 2 * HWN;
        const float* __restrict__ u = twth + (size_t)b * 2 * HWN;
        const float tx = t[hw], ty = t[HWN + hw];
        const float tw = u[hw], th = u[HWN + hw];

        const float cx = (sigmoidf_(tx) + (float)xx) * 4.0f;
        const float cy = (sigmoidf_(ty) + (float)yy) * 4.0f;
        const float bw = expf(tw) * 4.0f;
        const float bh = expf(th) * 4.0f;

        const float inv = 1.0f / 512.0f;
        float x1 = (cx - bw * 0.5f) * inv;
        float y1 = (cy - bh * 0.5f) * inv;
        float x2 = (cx + bw * 0.5f) * inv;
        float y2 = (cy + bh * 0.5f) * inv;
        x1 = fminf(fmaxf(x1, 0.0f), 1.0f);
        y1 = fminf(fmaxf(y1, 0.0f), 1.0f);
        x2 = fminf(fmaxf(x2, 0.0f), 1.0f);
        y2 = fminf(fmaxf(y2, 0.0f), 1.0f);

        float* bb = out + 800 + (size_t)(b * KTOP + tid) * 4;
        bb[0] = x1; bb[1] = y1; bb[2] = x2; bb[3] = y2;
    }
}

extern "C" void kernel_launch(void* const* d_in, const int* in_sizes, int n_in,
                              void* d_out, int out_size, void* d_ws, size_t ws_size,
                              hipStream_t stream) {
    const float* cls_logits = (const float*)d_in[0];
    const float* txty       = (const float*)d_in[1];
    const float* twth       = (const float*)d_in[2];
    float* out = (float*)d_out;

    // ws: slab 4,194,304 | counts 256 B | lists 512*128*8 = 524,288
    ull* slab   = (ull*)d_ws;
    int* counts = (int*)((char*)d_ws + (size_t)BB * CAPB * 8);
    ull* lists  = (ull*)((char*)d_ws + (size_t)BB * CAPB * 8 + 256);

    hipMemsetAsync(counts, 0, BB * sizeof(int), stream);
    knms<<<BB * CC * NSTRIP, 256, 0, stream>>>(cls_logits, slab, counts);
    kred<<<BB * NSEG,        512, 0, stream>>>(slab, counts, lists);
    kfin<<<BB,              1024, 0, stream>>>(lists, txty, twth, out);
}

// Round 10
// 95.427 us; speedup vs baseline: 1.0449x; 1.0161x over previous
//
#include <hip/hip_runtime.h>
#include <hip/hip_bf16.h>
#include <math.h>

#define BB   8
#define CC   80
#define HH   128
#define WW   128
#define HWN  16384
#define KTOP 100
#define NSTRIP 8
#define SR   16
#define LR   (SR + 4)
#define SCAP 512
#define CAPB 65536          // per-batch slab capacity; real data ~52.4K (R6-R9 validated)
#define NSEG 64             // kred segments per batch; NSEG*1024 == CAPB

typedef unsigned long long ull;

__device__ __forceinline__ float sigmoidf_(float x) {
    // bitwise-matched vs jax.nn.sigmoid (R1/R3/R4/R6-R9)
    if (x >= 0.0f) return 1.0f / (1.0f + expf(-x));
    float e = expf(x);
    return e / (1.0f + e);
}

// value desc, class asc, hw asc; unique per (map,hw). Ordering == reference
// two-stage top-k (proof R2-R4, bitwise-validated through R9).
__device__ __forceinline__ ull makekey(float v, int cls, int hw) {
    return ((ull)__float_as_uint(v) << 21)
         | ((ull)(127 - cls) << 14)
         | (ull)(16383 - hw);
}

// ---- Kernel A: R4's proven two-pass NMS (49us incl. sort), sort deleted ----
__global__ __launch_bounds__(256) void knms(const float* __restrict__ logits,
                                            ull* __restrict__ slab,
                                            int* __restrict__ counts) {
    __shared__ __align__(16) float s[LR][WW];    // 10 KB sigmoid tile (halo-clamped)
    __shared__ __align__(16) float vm[SR][WW];   // 8 KB vertical 5-max
    __shared__ ull cand[SCAP];                   // 4 KB
    __shared__ int cnt, gbase;

    const int tid   = threadIdx.x;
    const int map   = blockIdx.x >> 3;           // b*CC + c
    const int strip = blockIdx.x & 7;
    const int cls   = map % CC;
    const int b     = map / CC;
    const int R0    = strip * SR;
    const float* __restrict__ src = logits + (size_t)map * HWN;
    if (tid == 0) cnt = 0;

    // stage sigmoid tile, float4, halo rows clamped (== -inf pad for window max)
    for (int v = tid; v < LR * 32; v += 256) {
        const int lr = v >> 5, c4 = (v & 31) << 2;
        int gr = R0 - 2 + lr;
        gr = gr < 0 ? 0 : (gr > HH - 1 ? HH - 1 : gr);
        const float4 f = *reinterpret_cast<const float4*>(src + (size_t)gr * WW + c4);
        float4 o;
        o.x = sigmoidf_(f.x); o.y = sigmoidf_(f.y);
        o.z = sigmoidf_(f.z); o.w = sigmoidf_(f.w);
        *reinterpret_cast<float4*>(&s[lr][c4]) = o;
    }
    __syncthreads();

    // vertical 5-max per column (scalar LDS reads — R4-proven codegen)
    for (int i = tid; i < SR * WW; i += 256) {
        const int r = i >> 7, c = i & 127;
        float m = fmaxf(fmaxf(s[r][c], s[r + 1][c]), fmaxf(s[r + 2][c], s[r + 3][c]));
        vm[r][c] = fmaxf(m, s[r + 4][c]);
    }
    __syncthreads();

    // horizontal 5-max + keep + block compact
    for (int i = tid; i < SR * WW; i += 256) {
        const int r = i >> 7, c = i & 127;
        const int cm2 = c - 2 < 0 ? 0 : c - 2;
        const int cm1 = c - 1 < 0 ? 0 : c - 1;
        const int cp1 = c + 1 > 127 ? 127 : c + 1;
        const int cp2 = c + 2 > 127 ? 127 : c + 2;
        float m = fmaxf(fmaxf(vm[r][cm2], vm[r][cm1]), fmaxf(vm[r][c], vm[r][cp1]));
        m = fmaxf(m, vm[r][cp2]);
        const float v = s[r + 2][c];
        if (v == m) {   // exact reference keep: sigma == 5x5 sigma-max
            const int slot = atomicAdd(&cnt, 1);
            if (slot < SCAP) cand[slot] = makekey(v, cls, ((R0 + r) << 7) | c);
        }
    }
    __syncthreads();

    const int n = cnt < SCAP ? cnt : SCAP;
    if (tid == 0) gbase = atomicAdd(counts + b, n);
    __syncthreads();
    const int gb = gbase;
    for (int i = tid; i < n; i += 256) {
        const int gi = gb + i;
        if (gi < CAPB) slab[(size_t)b * CAPB + gi] = cand[i];
    }
}

// ---- in-register wave bitonic helpers (64 lanes; R6-R9 validated) ----
__device__ __forceinline__ ull sort64_desc(ull v, int lane) {
    for (int k = 2; k <= 64; k <<= 1) {
        for (int j = k >> 1; j >= 1; j >>= 1) {
            const ull p = __shfl_xor(v, j, 64);
            const bool km = (((lane & k) == 0) != ((lane & j) != 0));
            v = (km == (p > v)) ? p : v;
        }
    }
    return v;
}

__device__ __forceinline__ void bmerge128(ull& a0, ull& a1, int lane) {
    const ull t0 = a0 > a1 ? a0 : a1;
    a1 = a0 > a1 ? a1 : a0;
    a0 = t0;
    for (int j = 32; j >= 1; j >>= 1) {
        const ull p0 = __shfl_xor(a0, j, 64);
        const ull p1 = __shfl_xor(a1, j, 64);
        const bool km = ((lane & j) == 0);
        a0 = (km == (p0 > a0)) ? p0 : a0;
        a1 = (km == (p1 > a1)) ? p1 : a1;
    }
}

// ---- Kernel B: per 1024-key slab segment -> sorted top-128 (R9 verbatim) ----
__global__ __launch_bounds__(512) void kred(const ull* __restrict__ slab,
                                            const int* __restrict__ counts,
                                            ull* __restrict__ lists) {
    __shared__ ull ls[8][128];
    const int tid = threadIdx.x, w = tid >> 6, lane = tid & 63;
    const int b = blockIdx.x >> 6, seg = blockIdx.x & (NSEG - 1);

    int n = counts[b];
    n = n < CAPB ? n : CAPB;
    int avail = n - seg * 1024;
    avail = avail < 0 ? 0 : (avail > 1024 ? 1024 : avail);
    const ull* __restrict__ base = slab + (size_t)b * CAPB + seg * 1024;

    ull a0 = 0ULL, a1 = 0ULL;
#pragma unroll
    for (int c = 0; c < 2; ++c) {
        const int idx = (w * 2 + c) * 64 + lane;
        ull v = (idx < avail) ? base[idx] : 0ULL;
        v = sort64_desc(v, lane);
        const ull rv = __shfl(v, 63 - lane, 64);
        a1 = a1 > rv ? a1 : rv;
        bmerge128(a0, a1, lane);
    }
    ls[w][lane] = a0;
    ls[w][64 + lane] = a1;

    for (int half = 4; half >= 1; half >>= 1) {
        __syncthreads();
        ull z0 = 0ULL, z1 = 0ULL;
        const bool act = (w < half);
        if (act) {
            const ull l0 = ls[2 * w][lane];
            const ull l1 = ls[2 * w][64 + lane];
            const ull r1r = ls[2 * w + 1][127 - lane];
            const ull r0r = ls[2 * w + 1][63 - lane];
            z0 = l0 > r1r ? l0 : r1r;
            z1 = l1 > r0r ? l1 : r0r;
            bmerge128(z0, z1, lane);
        }
        __syncthreads();
        if (act) { ls[w][lane] = z0; ls[w][64 + lane] = z1; }
    }
    __syncthreads();
    if (tid < 128)
        lists[(size_t)blockIdx.x * 128 + tid] = ls[0][tid];
}

// ---- Kernel C: per batch, 16 waves reg-merge 4 lists each from global,
//      then 4-round LDS tree (16 KB), then decode (8 blocks x 1024) ----
__global__ __launch_bounds__(1024) void kfin(const ull* __restrict__ lists,
                                             const float* __restrict__ txty,
                                             const float* __restrict__ twth,
                                             float* __restrict__ out) {
    __shared__ ull ls[16][128];                  // 16 KB
    const int tid = threadIdx.x, b = blockIdx.x;
    const int w = tid >> 6, lane = tid & 63;
    const ull* __restrict__ L = lists + (size_t)b * NSEG * 128;

    // wave w: merge lists 4w..4w+3 in registers (loads replace shuffles)
    const ull* __restrict__ l0 = L + (size_t)(4 * w) * 128;
    ull a0 = l0[lane], a1 = l0[64 + lane];
#pragma unroll
    for (int k = 1; k < 4; ++k) {
        const ull* __restrict__ lk = L + (size_t)(4 * w + k) * 128;
        const ull r0 = lk[127 - lane];           // vs a0 (valley pairing)
        const ull r1 = lk[63 - lane];            // vs a1
        a0 = a0 > r0 ? a0 : r0;
        a1 = a1 > r1 ? a1 : r1;
        bmerge128(a0, a1, lane);
    }
    ls[w][lane] = a0;
    ls[w][64 + lane] = a1;

    // tree merge 16 -> 1
    for (int half = 8; half >= 1; half >>= 1) {
        __syncthreads();
        ull z0 = 0ULL, z1 = 0ULL;
        const bool act = (w < half);
        if (act) {
            const ull t0 = ls[2 * w][lane];
            const ull t1 = ls[2 * w][64 + lane];
            const ull r1r = ls[2 * w + 1][127 - lane];
            const ull r0r = ls[2 * w + 1][63 - lane];
            z0 = t0 > r1r ? t0 : r1r;
            z1 = t1 > r0r ? t1 : r0r;
            bmerge128(z0, z1, lane);
        }
        __syncthreads();
        if (act) { ls[w][lane] = z0; ls[w][64 + lane] = z1; }
    }
    __syncthreads();

    if (tid < KTOP) {
        const ull key = ls[0][tid];
        const int hw  = 16383 - (int)(key & 0x3FFFULL);
        const int cls = 127 - (int)((key >> 14) & 0x7FULL);
        const float sc = __uint_as_float((unsigned int)(key >> 21));

        // out layout (float32): score[0..800) | bbox[800..4000) | inds[4000..4800) | clses[4800..5600)
        out[b * KTOP + tid]        = sc;
        out[4000 + b * KTOP + tid] = (float)hw;
        out[4800 + b * KTOP + tid] = (float)cls;

        const int xx = hw & 127, yy = hw >> 7;
        const float* __restrict__ t = txty + (size_t)b * 2 * HWN;
        const float* __restrict__ u = twth + (size_t)b * 2 * HWN;
        const float tx = t[hw], ty = t[HWN + hw];
        const float tw = u[hw], th = u[HWN + hw];

        const float cx = (sigmoidf_(tx) + (float)xx) * 4.0f;
        const float cy = (sigmoidf_(ty) + (float)yy) * 4.0f;
        const float bw = expf(tw) * 4.0f;
        const float bh = expf(th) * 4.0f;

        const float inv = 1.0f / 512.0f;
        float x1 = (cx - bw * 0.5f) * inv;
        float y1 = (cy - bh * 0.5f) * inv;
        float x2 = (cx + bw * 0.5f) * inv;
        float y2 = (cy + bh * 0.5f) * inv;
        x1 = fminf(fmaxf(x1, 0.0f), 1.0f);
        y1 = fminf(fmaxf(y1, 0.0f), 1.0f);
        x2 = fminf(fmaxf(x2, 0.0f), 1.0f);
        y2 = fminf(fmaxf(y2, 0.0f), 1.0f);

        float* bb = out + 800 + (size_t)(b * KTOP + tid) * 4;
        bb[0] = x1; bb[1] = y1; bb[2] = x2; bb[3] = y2;
    }
}

extern "C" void kernel_launch(void* const* d_in, const int* in_sizes, int n_in,
                              void* d_out, int out_size, void* d_ws, size_t ws_size,
                              hipStream_t stream) {
    const float* cls_logits = (const float*)d_in[0];
    const float* txty       = (const float*)d_in[1];
    const float* twth       = (const float*)d_in[2];
    float* out = (float*)d_out;

    // ws: slab 4,194,304 | counts 256 B | lists 512*128*8 = 524,288
    ull* slab   = (ull*)d_ws;
    int* counts = (int*)((char*)d_ws + (size_t)BB * CAPB * 8);
    ull* lists  = (ull*)((char*)d_ws + (size_t)BB * CAPB * 8 + 256);

    hipMemsetAsync(counts, 0, BB * sizeof(int), stream);
    knms<<<BB * CC * NSTRIP, 256, 0, stream>>>(cls_logits, slab, counts);
    kred<<<BB * NSEG,        512, 0, stream>>>(slab, counts, lists);
    kfin<<<BB,              1024, 0, stream>>>(lists, txty, twth, out);
}

// Round 11
// 54.861 us; speedup vs baseline: 1.8176x; 1.7394x over previous
//
#include <hip/hip_runtime.h>
#include <hip/hip_bf16.h>
#include <math.h>

#define BB   8
#define CC   80
#define HH   128
#define WW   128
#define HWN  16384
#define KTOP 100
#define NSTRIP 8
#define SR   16
#define LR   (SR + 4)
#define SCAP 512
#define REG  100        // fixed per-strip region: strip lex-top-100 superset-suffices

typedef unsigned long long ull;

__device__ __forceinline__ float sigmoidf_(float x) {
    // bitwise-matched vs jax.nn.sigmoid (R1/R3/R4/R6-R10)
    if (x >= 0.0f) return 1.0f / (1.0f + expf(-x));
    float e = expf(x);
    return e / (1.0f + e);
}

// value desc, class asc, hw asc; unique per (map,hw). Ordering == reference
// two-stage top-k (proof R2-R4, bitwise-validated through R10).
__device__ __forceinline__ ull makekey(float v, int cls, int hw) {
    return ((ull)__float_as_uint(v) << 21)
         | ((ull)(127 - cls) << 14)
         | (ull)(16383 - hw);
}

#define BITONIC_DESC(arr, N2, NTHR)                                         \
    for (int k_ = 2; k_ <= (N2); k_ <<= 1) {                                \
        for (int j_ = k_ >> 1; j_ > 0; j_ >>= 1) {                          \
            for (int i_ = threadIdx.x; i_ < (N2); i_ += (NTHR)) {           \
                const int ixj_ = i_ ^ j_;                                   \
                if (ixj_ > i_) {                                            \
                    ull a_ = (arr)[i_], b_ = (arr)[ixj_];                   \
                    if (((i_ & k_) == 0) ? (a_ < b_) : (a_ > b_)) {         \
                        (arr)[i_] = b_; (arr)[ixj_] = a_;                   \
                    }                                                       \
                }                                                           \
            }                                                               \
            __syncthreads();                                                \
        }                                                                   \
    }

// ---- Kernel A: two-pass 5x5 NMS; fixed-region write, NO global atomics ----
// (R4->R10 lesson: 5120 blocks atomicAdd-ing 8 counters in one cache line
//  across 8 XCDs cost ~20us of barrier-serialized line bouncing.)
__global__ __launch_bounds__(256) void knms(const float* __restrict__ logits,
                                            ull* __restrict__ slab,
                                            int* __restrict__ scount) {
    __shared__ __align__(16) float s[LR][WW];    // 10 KB sigmoid tile (halo-clamped)
    __shared__ __align__(16) float vm[SR][WW];   // 8 KB vertical 5-max
    __shared__ ull cand[SCAP];                   // 4 KB
    __shared__ int cnt;

    const int tid   = threadIdx.x;
    const int map   = blockIdx.x >> 3;           // b*CC + c
    const int strip = blockIdx.x & 7;
    const int cls   = map % CC;
    const int R0    = strip * SR;
    const float* __restrict__ src = logits + (size_t)map * HWN;
    if (tid == 0) cnt = 0;

    // stage sigmoid tile, float4, halo rows clamped (== -inf pad for window max)
    for (int v = tid; v < LR * 32; v += 256) {
        const int lr = v >> 5, c4 = (v & 31) << 2;
        int gr = R0 - 2 + lr;
        gr = gr < 0 ? 0 : (gr > HH - 1 ? HH - 1 : gr);
        const float4 f = *reinterpret_cast<const float4*>(src + (size_t)gr * WW + c4);
        float4 o;
        o.x = sigmoidf_(f.x); o.y = sigmoidf_(f.y);
        o.z = sigmoidf_(f.z); o.w = sigmoidf_(f.w);
        *reinterpret_cast<float4*>(&s[lr][c4]) = o;
    }
    __syncthreads();

    // vertical 5-max, quad-vectorized (b128 LDS reads)
    for (int i = tid; i < SR * 32; i += 256) {
        const int r = i >> 5, c4 = (i & 31) << 2;
        const float4 r0 = *reinterpret_cast<const float4*>(&s[r    ][c4]);
        const float4 r1 = *reinterpret_cast<const float4*>(&s[r + 1][c4]);
        const float4 r2 = *reinterpret_cast<const float4*>(&s[r + 2][c4]);
        const float4 r3 = *reinterpret_cast<const float4*>(&s[r + 3][c4]);
        const float4 r4 = *reinterpret_cast<const float4*>(&s[r + 4][c4]);
        float4 m;
        m.x = fmaxf(fmaxf(r0.x, r1.x), fmaxf(fmaxf(r2.x, r3.x), r4.x));
        m.y = fmaxf(fmaxf(r0.y, r1.y), fmaxf(fmaxf(r2.y, r3.y), r4.y));
        m.z = fmaxf(fmaxf(r0.z, r1.z), fmaxf(fmaxf(r2.z, r3.z), r4.z));
        m.w = fmaxf(fmaxf(r0.w, r1.w), fmaxf(fmaxf(r2.w, r3.w), r4.w));
        *reinterpret_cast<float4*>(&vm[r][c4]) = m;
    }
    __syncthreads();

    // horizontal 5-max, quad-vectorized, NAMED SCALARS ONLY (no wv[] array:
    // runtime-indexed arrays -> scratch demotion, rule #20)
    for (int i = tid; i < SR * 32; i += 256) {
        const int r = i >> 5, c4 = (i & 31) << 2;
        const float4 M = *reinterpret_cast<const float4*>(&vm[r][c4]);
        float Lz = -INFINITY, Lw = -INFINITY;
        if (c4 >= 4) {
            const float4 L = *reinterpret_cast<const float4*>(&vm[r][c4 - 4]);
            Lz = L.z; Lw = L.w;
        }
        float Rx = -INFINITY, Ry = -INFINITY;
        if (c4 <= WW - 8) {
            const float4 R = *reinterpret_cast<const float4*>(&vm[r][c4 + 4]);
            Rx = R.x; Ry = R.y;
        }
        const float4 cen = *reinterpret_cast<const float4*>(&s[r + 2][c4]);
        const float mxy = fmaxf(M.x, M.y), mzw = fmaxf(M.z, M.w);
        const float m0 = fmaxf(fmaxf(Lz, Lw), fmaxf(mxy, M.z));
        const float m1 = fmaxf(Lw, fmaxf(mxy, mzw));
        const float m2 = fmaxf(fmaxf(mxy, mzw), Rx);
        const float m3 = fmaxf(fmaxf(M.y, mzw), fmaxf(Rx, Ry));
        const int hwb = ((R0 + r) << 7) | c4;
        if (cen.x == m0) { const int t = atomicAdd(&cnt, 1); if (t < SCAP) cand[t] = makekey(cen.x, cls, hwb); }
        if (cen.y == m1) { const int t = atomicAdd(&cnt, 1); if (t < SCAP) cand[t] = makekey(cen.y, cls, hwb + 1); }
        if (cen.z == m2) { const int t = atomicAdd(&cnt, 1); if (t < SCAP) cand[t] = makekey(cen.z, cls, hwb + 2); }
        if (cen.w == m3) { const int t = atomicAdd(&cnt, 1); if (t < SCAP) cand[t] = makekey(cen.w, cls, hwb + 3); }
    }
    __syncthreads();

    const int n = cnt < SCAP ? cnt : SCAP;
    ull* __restrict__ dst = slab + (size_t)blockIdx.x * REG;
    if (n <= REG) {
        // fast path (overwhelmingly common, n~82): unsorted write + count
        for (int i = tid; i < n; i += 256) dst[i] = cand[i];
        if (tid == 0) scount[blockIdx.x] = n;
    } else {
        // rare path: exact lex-top-100 via in-LDS bitonic (R4-proven)
        int n2 = 128;
        while (n2 < n) n2 <<= 1;
        for (int i = tid; i < n2; i += 256) if (i >= n) cand[i] = 0ULL;
        __syncthreads();
        BITONIC_DESC(cand, n2, 256);
        for (int i = tid; i < REG; i += 256) dst[i] = cand[i];
        if (tid == 0) scount[blockIdx.x] = REG;
    }
}

// ---- in-register wave bitonic helpers (64 lanes; R6-R10 validated) ----
__device__ __forceinline__ ull sort64_desc(ull v, int lane) {
    for (int k = 2; k <= 64; k <<= 1) {
        for (int j = k >> 1; j >= 1; j >>= 1) {
            const ull p = __shfl_xor(v, j, 64);
            const bool km = (((lane & k) == 0) != ((lane & j) != 0));
            v = (km == (p > v)) ? p : v;
        }
    }
    return v;
}

__device__ __forceinline__ void bmerge128(ull& a0, ull& a1, int lane) {
    const ull t0 = a0 > a1 ? a0 : a1;
    a1 = a0 > a1 ? a1 : a0;
    a0 = t0;
    for (int j = 32; j >= 1; j >>= 1) {
        const ull p0 = __shfl_xor(a0, j, 64);
        const ull p1 = __shfl_xor(a1, j, 64);
        const bool km = ((lane & j) == 0);
        a0 = (km == (p0 > a0)) ? p0 : a0;
        a1 = (km == (p1 > a1)) ? p1 : a1;
    }
}

// ---- Kernel B: per map (640 blocks): 8 waves sort one strip each, merge -> top-128 ----
__global__ __launch_bounds__(512) void kred(const ull* __restrict__ slab,
                                            const int* __restrict__ scount,
                                            ull* __restrict__ lists) {
    __shared__ ull ls[8][128];
    const int tid = threadIdx.x, w = tid >> 6, lane = tid & 63;
    const int map = blockIdx.x;
    const int sg = map * NSTRIP + w;             // global strip id for this wave

    const int n = scount[sg];                    // broadcast load (wave-uniform addr)
    const ull* __restrict__ base = slab + (size_t)sg * REG;

    ull a0 = 0ULL, a1 = 0ULL;
#pragma unroll
    for (int c = 0; c < 2; ++c) {
        const int idx = c * 64 + lane;
        ull v = (idx < n) ? base[idx] : 0ULL;
        v = sort64_desc(v, lane);
        const ull rv = __shfl(v, 63 - lane, 64);
        a1 = a1 > rv ? a1 : rv;
        bmerge128(a0, a1, lane);
    }
    ls[w][lane] = a0;
    ls[w][64 + lane] = a1;

    // merge 8 strip lists -> map top-128 (three rounds)
    for (int half = 4; half >= 1; half >>= 1) {
        __syncthreads();
        ull z0 = 0ULL, z1 = 0ULL;
        const bool act = (w < half);
        if (act) {
            const ull l0 = ls[2 * w][lane];
            const ull l1 = ls[2 * w][64 + lane];
            const ull r1r = ls[2 * w + 1][127 - lane];
            const ull r0r = ls[2 * w + 1][63 - lane];
            z0 = l0 > r1r ? l0 : r1r;
            z1 = l1 > r0r ? l1 : r0r;
            bmerge128(z0, z1, lane);
        }
        __syncthreads();
        if (act) { ls[w][lane] = z0; ls[w][64 + lane] = z1; }
    }
    __syncthreads();
    if (tid < 128)
        lists[(size_t)map * 128 + tid] = ls[0][tid];
}

// ---- Kernel C: per batch: 16 waves reg-merge 5 map-lists each, tree, decode ----
__global__ __launch_bounds__(1024) void kfin(const ull* __restrict__ lists,
                                             const float* __restrict__ txty,
                                             const float* __restrict__ twth,
                                             float* __restrict__ out) {
    __shared__ ull ls[16][128];                  // 16 KB
    const int tid = threadIdx.x, b = blockIdx.x;
    const int w = tid >> 6, lane = tid & 63;
    const ull* __restrict__ L = lists + (size_t)b * CC * 128;

    // wave w: merge map-lists 5w..5w+4 in registers (reversed loads as valley)
    const ull* __restrict__ l0 = L + (size_t)(5 * w) * 128;
    ull a0 = l0[lane], a1 = l0[64 + lane];
#pragma unroll
    for (int k = 1; k < 5; ++k) {
        const ull* __restrict__ lk = L + (size_t)(5 * w + k) * 128;
        const ull r0 = lk[127 - lane];
        const ull r1 = lk[63 - lane];
        a0 = a0 > r0 ? a0 : r0;
        a1 = a1 > r1 ? a1 : r1;
        bmerge128(a0, a1, lane);
    }
    ls[w][lane] = a0;
    ls[w][64 + lane] = a1;

    // tree merge 16 -> 1
    for (int half = 8; half >= 1; half >>= 1) {
        __syncthreads();
        ull z0 = 0ULL, z1 = 0ULL;
        const bool act = (w < half);
        if (act) {
            const ull t0 = ls[2 * w][lane];
            const ull t1 = ls[2 * w][64 + lane];
            const ull r1r = ls[2 * w + 1][127 - lane];
            const ull r0r = ls[2 * w + 1][63 - lane];
            z0 = t0 > r1r ? t0 : r1r;
            z1 = t1 > r0r ? t1 : r0r;
            bmerge128(z0, z1, lane);
        }
        __syncthreads();
        if (act) { ls[w][lane] = z0; ls[w][64 + lane] = z1; }
    }
    __syncthreads();

    if (tid < KTOP) {
        const ull key = ls[0][tid];
        const int hw  = 16383 - (int)(key & 0x3FFFULL);
        const int cls = 127 - (int)((key >> 14) & 0x7FULL);
        const float sc = __uint_as_float((unsigned int)(key >> 21));

        // out layout (float32): score[0..800) | bbox[800..4000) | inds[4000..4800) | clses[4800..5600)
        out[b * KTOP + tid]        = sc;
        out[4000 + b * KTOP + tid] = (float)hw;
        out[4800 + b * KTOP + tid] = (float)cls;

        const int xx = hw & 127, yy = hw >> 7;
        const float* __restrict__ t = txty + (size_t)b * 2 * HWN;
        const float* __restrict__ u = twth + (size_t)b * 2 * HWN;
        const float tx = t[hw], ty = t[HWN + hw];
        const float tw = u[hw], th = u[HWN + hw];

        const float cx = (sigmoidf_(tx) + (float)xx) * 4.0f;
        const float cy = (sigmoidf_(ty) + (float)yy) * 4.0f;
        const float bw = expf(tw) * 4.0f;
        const float bh = expf(th) * 4.0f;

        const float inv = 1.0f / 512.0f;
        float x1 = (cx - bw * 0.5f) * inv;
        float y1 = (cy - bh * 0.5f) * inv;
        float x2 = (cx + bw * 0.5f) * inv;
        float y2 = (cy + bh * 0.5f) * inv;
        x1 = fminf(fmaxf(x1, 0.0f), 1.0f);
        y1 = fminf(fmaxf(y1, 0.0f), 1.0f);
        x2 = fminf(fmaxf(x2, 0.0f), 1.0f);
        y2 = fminf(fmaxf(y2, 0.0f), 1.0f);

        float* bb = out + 800 + (size_t)(b * KTOP + tid) * 4;
        bb[0] = x1; bb[1] = y1; bb[2] = x2; bb[3] = y2;
    }
}

extern "C" void kernel_launch(void* const* d_in, const int* in_sizes, int n_in,
                              void* d_out, int out_size, void* d_ws, size_t ws_size,
                              hipStream_t stream) {
    const float* cls_logits = (const float*)d_in[0];
    const float* txty       = (const float*)d_in[1];
    const float* twth       = (const float*)d_in[2];
    float* out = (float*)d_out;

    // ws layout (bytes):
    //   slab:   5120 strips * 100 * 8 = 4,096,000
    //   scount: 5120 * 4             =    20,480   @ 4,096,000
    //   lists:  640 * 128 * 8        =   655,360   @ 4,116,480
    // total 4,771,840 — every byte read is written first (no memset needed)
    ull* slab   = (ull*)d_ws;
    int* scount = (int*)((char*)d_ws + 4096000);
    ull* lists  = (ull*)((char*)d_ws + 4116480);

    knms<<<BB * CC * NSTRIP, 256, 0, stream>>>(cls_logits, slab, scount);
    kred<<<BB * CC,          512, 0, stream>>>(slab, scount, lists);
    kfin<<<BB,              1024, 0, stream>>>(lists, txty, twth, out);
}